// Round 1
// baseline (515.113 us; speedup 1.0000x reference)
//
#include <hip/hip_runtime.h>
#include <hip/hip_fp16.h>
#include <stdint.h>

typedef _Float16 f16x8 __attribute__((ext_vector_type(8)));
typedef _Float16 f16x2 __attribute__((ext_vector_type(2)));
typedef float f32x4 __attribute__((ext_vector_type(4)));

// fallback-path tile (legacy 128^2 kernel)
#define BM 128
#define BN 128
#define BK 64

// main-path tile: 256^2, 8 waves, BK=32, 4 LDS K-tile buffers (deep pipeline)
#define GBM 256
#define GBN 256
#define GBK 32

// ---------- async global->LDS, 16B per lane (wave-uniform LDS base + lane*16) ----------
__device__ __forceinline__ void async_copy16(const void* g, void* l) {
  __builtin_amdgcn_global_load_lds(
      (__attribute__((address_space(1))) void*)(g),
      (__attribute__((address_space(3))) void*)(l),
      16, 0, 0);
}

// ---------- grid-stride fp32 -> fp16 (used for W ~4us and A ~35us; A lands in d_out) ----------
__global__ __launch_bounds__(256) void cvt_f32_f16(const float* __restrict__ in,
                                                   _Float16* __restrict__ out,
                                                   size_t n8) {
  const size_t stride = (size_t)gridDim.x * 256;
  for (size_t i = (size_t)blockIdx.x * 256 + threadIdx.x; i < n8; i += stride) {
    const float4* s = (const float4*)in + i * 2;
    float4 u = s[0];
    float4 v = s[1];
    f16x8 h;
    h[0] = (_Float16)u.x; h[1] = (_Float16)u.y; h[2] = (_Float16)u.z; h[3] = (_Float16)u.w;
    h[4] = (_Float16)v.x; h[5] = (_Float16)v.y; h[6] = (_Float16)v.z; h[7] = (_Float16)v.w;
    ((f16x8*)out)[i] = h;
  }
}

// ---------- stage one 256x32 fp16 tile (16 KB) via 2 global_load_lds rounds ----------
// LDS layout: [row][4 chunks of 8 halves]; chunk position p of row r holds SOURCE chunk
// p ^ ((r>>1)&3)  -> b128 frag reads spread 16 lanes over 8 distinct 16B slots (2-way = free).
// Source side is pre-swizzled (m173 pattern): LDS dest stays linear for global_load_lds.
__device__ __forceinline__ void stage32(const _Float16* __restrict__ src,
                                        _Float16* __restrict__ dst,
                                        int K, int wave, int lane) {
#pragma unroll
  for (int i = 0; i < 2; ++i) {
    const int basechunk = i * 512 + wave * 64;   // wave-uniform LDS base
    const int g   = basechunk + lane;            // chunk 0..1023
    const int row = g >> 2;
    const int sc  = (g & 3) ^ ((row >> 1) & 3);  // swizzled source chunk
    async_copy16(src + (size_t)row * K + sc * 8, dst + basechunk * 8);
  }
}

// ---------- main GEMM: H = A[M,K](fp16) * W[N,K]^T(fp16) + bias; fused column stats ----------
// 256x256 tile, 8 waves (2Mx4N), BK=32, 4 LDS buffers (128 KB), staging 3 K-tiles ahead.
// Per K-tile: 2 phases x {2 gload_lds prefetch(t+3) | 4-8 ds_read_b128 | barrier |
// lgkmcnt(0) | setprio(1) 16 MFMA setprio(0) | barrier}; s_waitcnt vmcnt(8) ONCE per
// K-tile (never 0 in steady state; epilogue drains 8->4->0).  Safety invariants:
//  - tile t reads gated by iter(t-1)-end vmcnt(8)+barrier (tiles <= t landed)
//  - stage(t+3) overwrites buf (t-1)&3; its last reads drained (lgkmcnt pre-MFMA)
//    before the preceding barrier; sched_barrier(0) pins the hazard boundaries.
// XCD remap: 4 blocks sharing an A-panel (bn=0..3) land on one XCD, co-resident.
__global__ __launch_bounds__(512, 2) void gemm16(const _Float16* __restrict__ Ah,
                                                 const _Float16* __restrict__ Wh,
                                                 const float* __restrict__ bias,
                                                 _Float16* __restrict__ Hout,
                                                 float* __restrict__ psum,
                                                 float* __restrict__ psumsq,
                                                 int M, int N, int K) {
  __shared__ __attribute__((aligned(16))) _Float16 lsA[4][GBM * GBK];  // 64 KB
  __shared__ __attribute__((aligned(16))) _Float16 lsB[4][GBN * GBK];  // 64 KB

  const int tid  = threadIdx.x;
  const int wave = tid >> 6;
  const int lane = tid & 63;
  const int l16  = lane & 15;
  const int quad = lane >> 4;
  const int wr   = wave >> 2;   // 0..1  (M half)
  const int wc   = wave & 3;    // 0..3  (N quarter)

  // XCD-aware remap (bijective, nwg=512 % 8 == 0): bmT&7 == xcd, bn fastest within xcd
  const int li  = blockIdx.x;
  const int xcd = li & 7;
  const int jj  = li >> 3;
  const int bnT = jj & 3;
  const int bmT = xcd + (jj >> 2) * 8;
  const int bm  = bmT * GBM;
  const int bn  = bnT * GBN;

  const _Float16* Ag = Ah + (size_t)bm * K;
  const _Float16* Bg = Wh + (size_t)bn * K;

  f32x4 acc[8][4];
#pragma unroll
  for (int i = 0; i < 8; ++i)
#pragma unroll
    for (int j = 0; j < 4; ++j) acc[i][j] = (f32x4){0.f, 0.f, 0.f, 0.f};

  const int NT = K >> 5;  // 32 K-tiles

  // ---- prologue: stage tiles 0,1,2 (12 loads), wait for tile 0 (vmcnt 8) ----
#pragma unroll
  for (int t = 0; t < 3; ++t) {
    stage32(Ag + t * GBK, lsA[t], K, wave, lane);
    stage32(Bg + t * GBK, lsB[t], K, wave, lane);
  }
  asm volatile("s_waitcnt vmcnt(8)" ::: "memory");
  __builtin_amdgcn_s_barrier();
  __builtin_amdgcn_sched_barrier(0);

  // per-lane LDS frag offsets (halves). pos is i/j-independent: (r>>1)&3 == (l16>>1)&3.
  const int pos   = quad ^ ((l16 >> 1) & 3);
  const int abase = ((wr * 128 + l16) * 4 + pos) * 8;  // + i*512
  const int bbase = ((wc * 64 + l16) * 4 + pos) * 8;   // + j*512

#pragma unroll 1
  for (int t = 0; t < NT; ++t) {
    const _Float16* bufA = lsA[t & 3];
    const _Float16* bufB = lsB[t & 3];
    const int tp = t + 3;
    const bool st = tp < NT;

    // ---------------- phase A: prefetch A(t+3); read B + A-low; MFMA i=0..3 ----------------
    if (st) stage32(Ag + (size_t)tp * GBK, lsA[tp & 3], K, wave, lane);
    f16x8 bf[4], af[4];
#pragma unroll
    for (int j = 0; j < 4; ++j) bf[j] = *(const f16x8*)&bufB[bbase + j * 512];
#pragma unroll
    for (int i = 0; i < 4; ++i) af[i] = *(const f16x8*)&bufA[abase + i * 512];
    __builtin_amdgcn_s_barrier();
    asm volatile("s_waitcnt lgkmcnt(0)" ::: "memory");
    __builtin_amdgcn_sched_barrier(0);
    __builtin_amdgcn_s_setprio(1);
#pragma unroll
    for (int i = 0; i < 4; ++i)
#pragma unroll
      for (int j = 0; j < 4; ++j)
        acc[i][j] = __builtin_amdgcn_mfma_f32_16x16x32_f16(af[i], bf[j], acc[i][j], 0, 0, 0);
    __builtin_amdgcn_s_setprio(0);
    __builtin_amdgcn_s_barrier();
    __builtin_amdgcn_sched_barrier(0);

    // ---------------- phase B: prefetch B(t+3); read A-high; MFMA i=4..7 ----------------
    if (st) stage32(Bg + (size_t)tp * GBK, lsB[tp & 3], K, wave, lane);
    f16x8 af2[4];
#pragma unroll
    for (int i = 0; i < 4; ++i) af2[i] = *(const f16x8*)&bufA[abase + (i + 4) * 512];
    __builtin_amdgcn_s_barrier();
    asm volatile("s_waitcnt lgkmcnt(0)" ::: "memory");
    __builtin_amdgcn_sched_barrier(0);
    __builtin_amdgcn_s_setprio(1);
#pragma unroll
    for (int i = 0; i < 4; ++i)
#pragma unroll
      for (int j = 0; j < 4; ++j)
        acc[i + 4][j] = __builtin_amdgcn_mfma_f32_16x16x32_f16(af2[i], bf[j], acc[i + 4][j], 0, 0, 0);
    __builtin_amdgcn_s_setprio(0);

    // ---- iter end: counted drain (tiles t+2,t+3 stay in flight), then barrier ----
    if (t < NT - 3)       asm volatile("s_waitcnt vmcnt(8)" ::: "memory");
    else if (t == NT - 3) asm volatile("s_waitcnt vmcnt(4)" ::: "memory");
    else if (t == NT - 2) asm volatile("s_waitcnt vmcnt(0)" ::: "memory");
    __builtin_amdgcn_s_barrier();
    __builtin_amdgcn_sched_barrier(0);
  }

  // ---- epilogue: bias, per-column partial stats, H2 pair-interleaved fp16 store ----
  f16x2* H2 = (f16x2*)Hout;
#pragma unroll
  for (int j = 0; j < 4; ++j) {
    const int c = bn + wc * 64 + j * 16 + l16;
    const float bv = bias[c];
    float s = 0.f, s2 = 0.f;
#pragma unroll
    for (int i = 0; i < 8; ++i) {
      const int r = bm + wr * 128 + i * 16 + quad * 4;   // always even
      f32x4 v = acc[i][j];
      const float v0 = v[0] + bv, v1 = v[1] + bv, v2 = v[2] + bv, v3 = v[3] + bv;
      s  += v0 + v1 + v2 + v3;
      s2 += v0 * v0 + v1 * v1 + v2 * v2 + v3 * v3;
      const size_t d0 = (size_t)(r >> 1) * N + c;
      H2[d0]     = (f16x2){(_Float16)v0, (_Float16)v1};
      H2[d0 + N] = (f16x2){(_Float16)v2, (_Float16)v3};
    }
    s  += __shfl_xor(s, 16, 64);  s  += __shfl_xor(s, 32, 64);
    s2 += __shfl_xor(s2, 16, 64); s2 += __shfl_xor(s2, 32, 64);
    if (quad == 0) {
      const size_t slot = (size_t)(bmT * 2 + wr) * N + c;  // [slot][c], S = M/128
      psum[slot]   = s;
      psumsq[slot] = s2;
    }
  }
}

// ---------- fallback GEMM (fp32 inputs, in-register cvt both, atomic stats) ----------
__global__ __launch_bounds__(256) void gemm_fallback(const float* __restrict__ Af,
                                                     const float* __restrict__ Wf,
                                                     const float* __restrict__ bias,
                                                     float* __restrict__ C,
                                                     float* __restrict__ sum,
                                                     float* __restrict__ sumsq,
                                                     int M, int N, int K) {
  __shared__ __attribute__((aligned(16))) _Float16 lsA[BM * BK];
  __shared__ __attribute__((aligned(16))) _Float16 lsB[BN * BK];
  const int tid  = threadIdx.x;
  const int wave = tid >> 6;
  const int lane = tid & 63;
  const int wrow = (wave >> 1) * 64;
  const int wcol = (wave & 1) * 64;
  const int l16  = lane & 15;
  const int quad = lane >> 4;
  const int bm = blockIdx.y * BM;
  const int bn = blockIdx.x * BN;

  f32x4 acc[4][4];
#pragma unroll
  for (int i = 0; i < 4; ++i)
#pragma unroll
    for (int j = 0; j < 4; ++j) acc[i][j] = (f32x4){0.f, 0.f, 0.f, 0.f};

  for (int k0 = 0; k0 < K; k0 += BK) {
#pragma unroll
    for (int i = 0; i < 4; ++i) {
      const int g   = i * 256 + tid;
      const int row = g >> 3;
      const int kc8 = g & 7;
      const int slot = row * 8 + (kc8 ^ (row & 7));
      {
        const float* src = Af + (size_t)(bm + row) * K + k0 + kc8 * 8;
        float4 u = *(const float4*)src;
        float4 v = *(const float4*)(src + 4);
        f16x8 h;
        h[0] = (_Float16)u.x; h[1] = (_Float16)u.y; h[2] = (_Float16)u.z; h[3] = (_Float16)u.w;
        h[4] = (_Float16)v.x; h[5] = (_Float16)v.y; h[6] = (_Float16)v.z; h[7] = (_Float16)v.w;
        *(f16x8*)&lsA[slot * 8] = h;
      }
      {
        const float* src = Wf + (size_t)(bn + row) * K + k0 + kc8 * 8;
        float4 u = *(const float4*)src;
        float4 v = *(const float4*)(src + 4);
        f16x8 h;
        h[0] = (_Float16)u.x; h[1] = (_Float16)u.y; h[2] = (_Float16)u.z; h[3] = (_Float16)u.w;
        h[4] = (_Float16)v.x; h[5] = (_Float16)v.y; h[6] = (_Float16)v.z; h[7] = (_Float16)v.w;
        *(f16x8*)&lsB[slot * 8] = h;
      }
    }
    __syncthreads();
#pragma unroll
    for (int kk = 0; kk < BK; kk += 32) {
      f16x8 af[4], bf[4];
#pragma unroll
      for (int i = 0; i < 4; ++i) {
        const int r = wrow + i * 16 + l16;
        const int col = ((kk >> 3) + quad) ^ (l16 & 7);
        af[i] = *(const f16x8*)&lsA[r * 64 + col * 8];
      }
#pragma unroll
      for (int j = 0; j < 4; ++j) {
        const int r = wcol + j * 16 + l16;
        const int col = ((kk >> 3) + quad) ^ (l16 & 7);
        bf[j] = *(const f16x8*)&lsB[r * 64 + col * 8];
      }
#pragma unroll
      for (int i = 0; i < 4; ++i)
#pragma unroll
        for (int j = 0; j < 4; ++j)
          acc[i][j] = __builtin_amdgcn_mfma_f32_16x16x32_f16(af[i], bf[j], acc[i][j], 0, 0, 0);
    }
    __syncthreads();
  }

#pragma unroll
  for (int j = 0; j < 4; ++j) {
    const int c = bn + wcol + j * 16 + l16;
    const float bv = bias[c];
    float s = 0.f, s2 = 0.f;
#pragma unroll
    for (int i = 0; i < 4; ++i) {
      const int r = bm + wrow + i * 16 + quad * 4;
      float* Cp = C + (size_t)r * N + c;
      f32x4 v = acc[i][j];
#pragma unroll
      for (int rr = 0; rr < 4; ++rr) {
        float val = v[rr] + bv;
        Cp[(size_t)rr * N] = val;
        s += val;
        s2 += val * val;
      }
    }
    s  += __shfl_xor(s, 16, 64);  s  += __shfl_xor(s, 32, 64);
    s2 += __shfl_xor(s2, 16, 64); s2 += __shfl_xor(s2, 32, 64);
    if (quad == 0) {
      atomicAdd(&sum[c], s);
      atomicAdd(&sumsq[c], s2);
    }
  }
}

// ---------- finalize from [slot][c] partials: one wave per column ----------
__global__ __launch_bounds__(256) void bn_finalize_wave(const float* __restrict__ psum,
                                                        const float* __restrict__ psumsq,
                                                        const float* __restrict__ gamma,
                                                        const float* __restrict__ beta,
                                                        float* __restrict__ scale,
                                                        float* __restrict__ shift,
                                                        float invB, int S, int D) {
  const int wave = threadIdx.x >> 6;
  const int lane = threadIdx.x & 63;
  const int c = blockIdx.x * 4 + wave;
  float s = 0.f, q = 0.f;
  for (int u = lane; u < S; u += 64) {
    s += psum[(size_t)u * D + c];
    q += psumsq[(size_t)u * D + c];
  }
#pragma unroll
  for (int o = 32; o > 0; o >>= 1) {
    s += __shfl_xor(s, o, 64);
    q += __shfl_xor(q, o, 64);
  }
  if (lane == 0) {
    float mean = s * invB;
    float var  = q * invB - mean * mean;
    float rstd = rsqrtf(var + 1e-5f);
    float sc = rstd * gamma[c];
    scale[c] = sc;
    shift[c] = beta[c] - mean * sc;
  }
}

// ---------- finalize from atomic sums (fallback) ----------
__global__ __launch_bounds__(256) void bn_finalize(const float* __restrict__ sum,
                                                   const float* __restrict__ sumsq,
                                                   const float* __restrict__ gamma,
                                                   const float* __restrict__ beta,
                                                   float* __restrict__ scale,
                                                   float* __restrict__ shift,
                                                   float invB) {
  const int c = blockIdx.x * 256 + threadIdx.x;
  float mean = sum[c] * invB;
  float var  = sumsq[c] * invB - mean * mean;
  float rstd = rsqrtf(var + 1e-5f);
  float sc = rstd * gamma[c];
  scale[c] = sc;
  shift[c] = beta[c] - mean * sc;
}

// ---------- BN + prior + sparsemax: one row per wave, H2 pair-interleaved fp16 ----------
__global__ __launch_bounds__(256) void bn_sparsemax_h2(const _Float16* __restrict__ H2,
                                                       const float* __restrict__ P,
                                                       const float* __restrict__ scale,
                                                       const float* __restrict__ shift,
                                                       float* __restrict__ out, int D) {
  const int wave = threadIdx.x >> 6;
  const int lane = threadIdx.x & 63;
  const int row = blockIdx.x * 4 + wave;
  const int rp  = row >> 1;
  const int par = row & 1;

  const f16x8* Hc = (const f16x8*)(H2 + (size_t)rp * 2 * D);
  const f32x4* P4 = (const f32x4*)(P + (size_t)row * D);
  const f32x4* SC = (const f32x4*)scale;
  const f32x4* SH = (const f32x4*)shift;

  f32x4 z[4];
  float tot = 0.f;
#pragma unroll
  for (int j = 0; j < 4; ++j) {
    const int idx = j * 64 + lane;
    f16x8 h = Hc[idx];
    f32x4 hv = {(float)h[par], (float)h[2 + par], (float)h[4 + par], (float)h[6 + par]};
    f32x4 zz = P4[idx] * (hv * SC[idx] + SH[idx]);
    z[j] = zz;
    tot += zz[0] + zz[1] + zz[2] + zz[3];
  }
#pragma unroll
  for (int o = 32; o > 0; o >>= 1) tot += __shfl_xor(tot, o, 64);

  float tau = (tot - 1.0f) / (float)D;
  float kprev = -1.0f;
  for (int it = 0; it < 64; ++it) {
    float s = 0.f, kf = 0.f;
#pragma unroll
    for (int j = 0; j < 4; ++j)
#pragma unroll
      for (int c = 0; c < 4; ++c) {
        float zz = z[j][c];
        if (zz > tau) { s += zz; kf += 1.0f; }
      }
#pragma unroll
    for (int o = 32; o > 0; o >>= 1) {
      s  += __shfl_xor(s, o, 64);
      kf += __shfl_xor(kf, o, 64);
    }
    tau = (s - 1.0f) / kf;
    if (kf == kprev) break;
    kprev = kf;
  }

  f32x4* O4 = (f32x4*)(out + (size_t)row * D);
#pragma unroll
  for (int j = 0; j < 4; ++j) {
    const int idx = j * 64 + lane;
    f32x4 o;
#pragma unroll
    for (int c = 0; c < 4; ++c) o[c] = fmaxf(z[j][c] - tau, 0.f);
    O4[idx] = o;
  }
}

// ---------- fp32 row-major variant (fallback path) ----------
__global__ __launch_bounds__(256) void bn_sparsemax_f32(const float* __restrict__ H,
                                                        const float* __restrict__ P,
                                                        const float* __restrict__ scale,
                                                        const float* __restrict__ shift,
                                                        float* __restrict__ out, int D) {
  const int wave = threadIdx.x >> 6;
  const int lane = threadIdx.x & 63;
  const int row = blockIdx.x * 4 + wave;
  const size_t rowoff = (size_t)row * D;
  const f32x4* H4 = (const f32x4*)(H + rowoff);
  const f32x4* P4 = (const f32x4*)(P + rowoff);
  const f32x4* SC = (const f32x4*)scale;
  const f32x4* SH = (const f32x4*)shift;

  f32x4 z[4];
  float tot = 0.f;
#pragma unroll
  for (int j = 0; j < 4; ++j) {
    const int idx = j * 64 + lane;
    f32x4 zz = P4[idx] * (H4[idx] * SC[idx] + SH[idx]);
    z[j] = zz;
    tot += zz[0] + zz[1] + zz[2] + zz[3];
  }
#pragma unroll
  for (int o = 32; o > 0; o >>= 1) tot += __shfl_xor(tot, o, 64);

  float tau = (tot - 1.0f) / (float)D;
  float kprev = -1.0f;
  for (int it = 0; it < 64; ++it) {
    float s = 0.f, kf = 0.f;
#pragma unroll
    for (int j = 0; j < 4; ++j)
#pragma unroll
      for (int c = 0; c < 4; ++c) {
        float zz = z[j][c];
        if (zz > tau) { s += zz; kf += 1.0f; }
      }
#pragma unroll
    for (int o = 32; o > 0; o >>= 1) {
      s  += __shfl_xor(s, o, 64);
      kf += __shfl_xor(kf, o, 64);
    }
    tau = (s - 1.0f) / kf;
    if (kf == kprev) break;
    kprev = kf;
  }

  f32x4* O4 = (f32x4*)(out + rowoff);
#pragma unroll
  for (int j = 0; j < 4; ++j) {
    const int idx = j * 64 + lane;
    f32x4 o;
#pragma unroll
    for (int c = 0; c < 4; ++c) o[c] = fmaxf(z[j][c] - tau, 0.f);
    O4[idx] = o;
  }
}

extern "C" void kernel_launch(void* const* d_in, const int* in_sizes, int n_in,
                              void* d_out, int out_size, void* d_ws, size_t ws_size,
                              hipStream_t stream) {
  const float* a     = (const float*)d_in[0];
  const float* p     = (const float*)d_in[1];
  const float* W     = (const float*)d_in[2];
  const float* b     = (const float*)d_in[3];
  const float* gamma = (const float*)d_in[4];
  const float* beta  = (const float*)d_in[5];
  float* out = (float*)d_out;

  const int D = in_sizes[3];           // 1024
  const int Brows = in_sizes[0] / D;   // 32768
  const int K = D, N = D;
  const size_t na = (size_t)Brows * D;
  const size_t nw = (size_t)D * D;
  const int S = (Brows / GBM) * 2;     // partial slots (256)

  // ws layout (~68 MB): [psum S*D][psumsq S*D][scale D][shift D][Wh fp16][H2 fp16]
  // A fp16 (64 MB) lives in d_out (only written by the final sparsemax kernel).
  const size_t statsB = (size_t)D * S * sizeof(float);            // 1 MB
  float* psum   = (float*)d_ws;
  float* psumsq = (float*)((char*)d_ws + statsB);
  float* wscale = (float*)((char*)d_ws + 2 * statsB);
  float* wshift = wscale + D;
  const size_t off_Wh = 2 * statsB + 16384;
  _Float16* Wh = (_Float16*)((char*)d_ws + off_Wh);
  _Float16* H2 = Wh + nw;
  const size_t need = off_Wh + (nw + na) * sizeof(_Float16);      // ~68 MB
  _Float16* Ah = (_Float16*)d_out;

  const bool shape_ok = (Brows % GBM) == 0 && ((Brows / GBM) % 8) == 0 &&
                        (N / GBN) == 4 && (N % GBN) == 0 &&
                        (K % GBK) == 0 && (K / GBK) >= 4;

  if (ws_size >= need && (size_t)out_size >= na * sizeof(_Float16) && shape_ok) {
    cvt_f32_f16<<<dim3(512), 256, 0, stream>>>(W, Wh, nw / 8);
    cvt_f32_f16<<<dim3(2048), 256, 0, stream>>>(a, Ah, na / 8);
    gemm16<<<dim3((Brows / GBM) * (N / GBN)), 512, 0, stream>>>(
        Ah, Wh, b, H2, psum, psumsq, Brows, N, K);
    bn_finalize_wave<<<dim3(D / 4), 256, 0, stream>>>(psum, psumsq, gamma, beta,
                                                      wscale, wshift,
                                                      1.0f / (float)Brows, S, D);
    bn_sparsemax_h2<<<dim3(Brows / 4), 256, 0, stream>>>(H2, p, wscale, wshift, out, D);
  } else {
    // fallback: atomic stats, fp32 H in d_out, in-register cvt of A and W
    float* wsum   = (float*)d_ws;
    float* wsumsq = wsum + D;
    float* fscale = wsum + 2 * D;
    float* fshift = wsum + 3 * D;
    hipMemsetAsync(d_ws, 0, 2 * D * sizeof(float), stream);
    gemm_fallback<<<dim3(N / BN, Brows / BM), 256, 0, stream>>>(
        a, W, b, out, wsum, wsumsq, Brows, N, K);
    bn_finalize<<<dim3(D / 256), 256, 0, stream>>>(wsum, wsumsq, gamma, beta, fscale, fshift,
                                                   1.0f / (float)Brows);
    bn_sparsemax_f32<<<dim3(Brows / 4), 256, 0, stream>>>(out, p, fscale, fshift, out, D);
  }
}

// Round 2
// 428.019 us; speedup vs baseline: 1.2035x; 1.2035x over previous
//
#include <hip/hip_runtime.h>
#include <hip/hip_fp16.h>
#include <stdint.h>

typedef _Float16 f16x8 __attribute__((ext_vector_type(8)));
typedef _Float16 f16x2 __attribute__((ext_vector_type(2)));
typedef float f32x4 __attribute__((ext_vector_type(4)));

// fallback-path tile (legacy 128^2 kernel)
#define BM 128
#define BN 128
#define BK 64

// main-path tile: 256^2, 8 waves, BK=32, 4 LDS K-tile buffers (deep pipeline)
#define GBM 256
#define GBN 256
#define GBK 32

// ---------- async global->LDS, 16B per lane (wave-uniform LDS base + lane*16) ----------
__device__ __forceinline__ void async_copy16(const void* g, void* l) {
  __builtin_amdgcn_global_load_lds(
      (__attribute__((address_space(1))) void*)(g),
      (__attribute__((address_space(3))) void*)(l),
      16, 0, 0);
}

// ---------- grid-stride fp32 -> fp16 (used for W ~4us and A ~35us; A lands in d_out) ----------
__global__ __launch_bounds__(256) void cvt_f32_f16(const float* __restrict__ in,
                                                   _Float16* __restrict__ out,
                                                   size_t n8) {
  const size_t stride = (size_t)gridDim.x * 256;
  for (size_t i = (size_t)blockIdx.x * 256 + threadIdx.x; i < n8; i += stride) {
    const float4* s = (const float4*)in + i * 2;
    float4 u = s[0];
    float4 v = s[1];
    f16x8 h;
    h[0] = (_Float16)u.x; h[1] = (_Float16)u.y; h[2] = (_Float16)u.z; h[3] = (_Float16)u.w;
    h[4] = (_Float16)v.x; h[5] = (_Float16)v.y; h[6] = (_Float16)v.z; h[7] = (_Float16)v.w;
    ((f16x8*)out)[i] = h;
  }
}

// ---------- stage one 256x32 fp16 tile (16 KB) via 2 global_load_lds rounds ----------
// LDS layout: [row][4 chunks of 8 halves]; chunk position p of row r holds SOURCE chunk
// p ^ ((r>>1)&3)  -> b128 frag reads spread the wave over 32 16B slots at exactly 2-way
// aliasing (free, m136). Source side is pre-swizzled (m173 pattern): LDS dest stays
// linear for global_load_lds (rule 21: linear dest + inverse-swz source + swz on read).
__device__ __forceinline__ void stage32(const _Float16* __restrict__ src,
                                        _Float16* __restrict__ dst,
                                        int K, int wave, int lane) {
#pragma unroll
  for (int i = 0; i < 2; ++i) {
    const int basechunk = i * 512 + wave * 64;   // wave-uniform LDS base
    const int g   = basechunk + lane;            // chunk 0..1023
    const int row = g >> 2;
    const int sc  = (g & 3) ^ ((row >> 1) & 3);  // swizzled source chunk
    async_copy16(src + (size_t)row * K + sc * 8, dst + basechunk * 8);
  }
}

// ---------- main GEMM: H = A[M,K](fp16) * W[N,K]^T(fp16) + bias; fused column stats ----------
// 256x256 tile, 8 waves (2Mx4N), BK=32, 4 LDS buffers (128 KB), staging 3 K-tiles ahead.
// Per K-tile: 2 phases x {2 gload_lds prefetch(t+3) | 4-8 ds_read_b128 | barrier |
// lgkmcnt(0) | setprio(1) 16 MFMA setprio(0) | barrier}; s_waitcnt vmcnt(8) ONCE per
// K-tile (never 0 in steady state; epilogue drains 8->4->0).  Safety invariants:
//  - tile t reads gated by iter(t-1)-end vmcnt(8)+barrier (tiles <= t+1 landed; the
//    barrier makes the per-wave vmcnt collective across all 8 waves)
//  - stage(t+3) overwrites buf (t-1)&3; its last reads drained (lgkmcnt pre-MFMA)
//    before the preceding barrier; sched_barrier(0) pins the hazard boundaries.
// XCD remap: 4 blocks sharing an A-panel (bnT=0..3) land on one XCD, co-resident.
__global__ __launch_bounds__(512, 2) void gemm16(const _Float16* __restrict__ Ah,
                                                 const _Float16* __restrict__ Wh,
                                                 const float* __restrict__ bias,
                                                 _Float16* __restrict__ Hout,
                                                 float* __restrict__ psum,
                                                 float* __restrict__ psumsq,
                                                 int M, int N, int K) {
  __shared__ __attribute__((aligned(16))) _Float16 lsA[4][GBM * GBK];  // 64 KB
  __shared__ __attribute__((aligned(16))) _Float16 lsB[4][GBN * GBK];  // 64 KB

  const int tid  = threadIdx.x;
  const int wave = tid >> 6;
  const int lane = tid & 63;
  const int l16  = lane & 15;
  const int quad = lane >> 4;
  const int wr   = wave >> 2;   // 0..1  (M half)
  const int wc   = wave & 3;    // 0..3  (N quarter)

  // XCD-aware remap (bijective, nwg=512 % 8 == 0): bmT&7 == xcd, bn fastest within xcd
  const int li  = blockIdx.x;
  const int xcd = li & 7;
  const int jj  = li >> 3;
  const int bnT = jj & 3;
  const int bmT = xcd + (jj >> 2) * 8;
  const int bm  = bmT * GBM;
  const int bn  = bnT * GBN;

  const _Float16* Ag = Ah + (size_t)bm * K;
  const _Float16* Bg = Wh + (size_t)bn * K;

  f32x4 acc[8][4];
#pragma unroll
  for (int i = 0; i < 8; ++i)
#pragma unroll
    for (int j = 0; j < 4; ++j) acc[i][j] = (f32x4){0.f, 0.f, 0.f, 0.f};

  const int NT = K >> 5;  // 32 K-tiles

  // ---- prologue: stage tiles 0,1,2 (12 loads/thread), wait for tile 0 (vmcnt 8) ----
#pragma unroll
  for (int t = 0; t < 3; ++t) {
    stage32(Ag + t * GBK, lsA[t], K, wave, lane);
    stage32(Bg + t * GBK, lsB[t], K, wave, lane);
  }
  asm volatile("s_waitcnt vmcnt(8)" ::: "memory");
  __builtin_amdgcn_s_barrier();
  __builtin_amdgcn_sched_barrier(0);

  // per-lane LDS frag offsets (halves). pos is i/j-independent: (r>>1)&3 == (l16>>1)&3.
  const int pos   = quad ^ ((l16 >> 1) & 3);
  const int abase = ((wr * 128 + l16) * 4 + pos) * 8;  // + i*512
  const int bbase = ((wc * 64 + l16) * 4 + pos) * 8;   // + j*512

#pragma unroll 1
  for (int t = 0; t < NT; ++t) {
    const _Float16* bufA = lsA[t & 3];
    const _Float16* bufB = lsB[t & 3];
    const int tp = t + 3;
    const bool st = tp < NT;

    // ---------------- phase A: prefetch A(t+3); read B + A-low; MFMA i=0..3 ----------------
    if (st) stage32(Ag + (size_t)tp * GBK, lsA[tp & 3], K, wave, lane);
    f16x8 bf[4], af[4];
#pragma unroll
    for (int j = 0; j < 4; ++j) bf[j] = *(const f16x8*)&bufB[bbase + j * 512];
#pragma unroll
    for (int i = 0; i < 4; ++i) af[i] = *(const f16x8*)&bufA[abase + i * 512];
    __builtin_amdgcn_s_barrier();
    asm volatile("s_waitcnt lgkmcnt(0)" ::: "memory");
    __builtin_amdgcn_sched_barrier(0);
    __builtin_amdgcn_s_setprio(1);
#pragma unroll
    for (int i = 0; i < 4; ++i)
#pragma unroll
      for (int j = 0; j < 4; ++j)
        acc[i][j] = __builtin_amdgcn_mfma_f32_16x16x32_f16(af[i], bf[j], acc[i][j], 0, 0, 0);
    __builtin_amdgcn_s_setprio(0);
    __builtin_amdgcn_s_barrier();
    __builtin_amdgcn_sched_barrier(0);

    // ---------------- phase B: prefetch B(t+3); read A-high; MFMA i=4..7 ----------------
    if (st) stage32(Bg + (size_t)tp * GBK, lsB[tp & 3], K, wave, lane);
    f16x8 af2[4];
#pragma unroll
    for (int i = 0; i < 4; ++i) af2[i] = *(const f16x8*)&bufA[abase + (i + 4) * 512];
    __builtin_amdgcn_s_barrier();
    asm volatile("s_waitcnt lgkmcnt(0)" ::: "memory");
    __builtin_amdgcn_sched_barrier(0);
    __builtin_amdgcn_s_setprio(1);
#pragma unroll
    for (int i = 0; i < 4; ++i)
#pragma unroll
      for (int j = 0; j < 4; ++j)
        acc[i + 4][j] = __builtin_amdgcn_mfma_f32_16x16x32_f16(af2[i], bf[j], acc[i + 4][j], 0, 0, 0);
    __builtin_amdgcn_s_setprio(0);

    // ---- iter end: counted drain (tiles t+2,t+3 stay in flight), then barrier ----
    if (t < NT - 3)       asm volatile("s_waitcnt vmcnt(8)" ::: "memory");
    else if (t == NT - 3) asm volatile("s_waitcnt vmcnt(4)" ::: "memory");
    else if (t == NT - 2) asm volatile("s_waitcnt vmcnt(0)" ::: "memory");
    __builtin_amdgcn_s_barrier();
    __builtin_amdgcn_sched_barrier(0);
  }

  // ---- epilogue: bias, per-column partial stats, H2 pair-interleaved fp16 store ----
  f16x2* H2 = (f16x2*)Hout;
#pragma unroll
  for (int j = 0; j < 4; ++j) {
    const int c = bn + wc * 64 + j * 16 + l16;
    const float bv = bias[c];
    float s = 0.f, s2 = 0.f;
#pragma unroll
    for (int i = 0; i < 8; ++i) {
      const int r = bm + wr * 128 + i * 16 + quad * 4;   // always even
      f32x4 v = acc[i][j];
      const float v0 = v[0] + bv, v1 = v[1] + bv, v2 = v[2] + bv, v3 = v[3] + bv;
      s  += v0 + v1 + v2 + v3;
      s2 += v0 * v0 + v1 * v1 + v2 * v2 + v3 * v3;
      const size_t d0 = (size_t)(r >> 1) * N + c;
      H2[d0]     = (f16x2){(_Float16)v0, (_Float16)v1};
      H2[d0 + N] = (f16x2){(_Float16)v2, (_Float16)v3};
    }
    s  += __shfl_xor(s, 16, 64);  s  += __shfl_xor(s, 32, 64);
    s2 += __shfl_xor(s2, 16, 64); s2 += __shfl_xor(s2, 32, 64);
    if (quad == 0) {
      const size_t slot = (size_t)(bmT * 2 + wr) * N + c;  // [slot][c], S = M/128
      psum[slot]   = s;
      psumsq[slot] = s2;
    }
  }
}

// ---------- fallback GEMM (fp32 inputs, in-register cvt both, atomic stats) ----------
__global__ __launch_bounds__(256) void gemm_fallback(const float* __restrict__ Af,
                                                     const float* __restrict__ Wf,
                                                     const float* __restrict__ bias,
                                                     float* __restrict__ C,
                                                     float* __restrict__ sum,
                                                     float* __restrict__ sumsq,
                                                     int M, int N, int K) {
  __shared__ __attribute__((aligned(16))) _Float16 lsA[BM * BK];
  __shared__ __attribute__((aligned(16))) _Float16 lsB[BN * BK];
  const int tid  = threadIdx.x;
  const int wave = tid >> 6;
  const int lane = tid & 63;
  const int wrow = (wave >> 1) * 64;
  const int wcol = (wave & 1) * 64;
  const int l16  = lane & 15;
  const int quad = lane >> 4;
  const int bm = blockIdx.y * BM;
  const int bn = blockIdx.x * BN;

  f32x4 acc[4][4];
#pragma unroll
  for (int i = 0; i < 4; ++i)
#pragma unroll
    for (int j = 0; j < 4; ++j) acc[i][j] = (f32x4){0.f, 0.f, 0.f, 0.f};

  for (int k0 = 0; k0 < K; k0 += BK) {
#pragma unroll
    for (int i = 0; i < 4; ++i) {
      const int g   = i * 256 + tid;
      const int row = g >> 3;
      const int kc8 = g & 7;
      const int slot = row * 8 + (kc8 ^ (row & 7));
      {
        const float* src = Af + (size_t)(bm + row) * K + k0 + kc8 * 8;
        float4 u = *(const float4*)src;
        float4 v = *(const float4*)(src + 4);
        f16x8 h;
        h[0] = (_Float16)u.x; h[1] = (_Float16)u.y; h[2] = (_Float16)u.z; h[3] = (_Float16)u.w;
        h[4] = (_Float16)v.x; h[5] = (_Float16)v.y; h[6] = (_Float16)v.z; h[7] = (_Float16)v.w;
        *(f16x8*)&lsA[slot * 8] = h;
      }
      {
        const float* src = Wf + (size_t)(bn + row) * K + k0 + kc8 * 8;
        float4 u = *(const float4*)src;
        float4 v = *(const float4*)(src + 4);
        f16x8 h;
        h[0] = (_Float16)u.x; h[1] = (_Float16)u.y; h[2] = (_Float16)u.z; h[3] = (_Float16)u.w;
        h[4] = (_Float16)v.x; h[5] = (_Float16)v.y; h[6] = (_Float16)v.z; h[7] = (_Float16)v.w;
        *(f16x8*)&lsB[slot * 8] = h;
      }
    }
    __syncthreads();
#pragma unroll
    for (int kk = 0; kk < BK; kk += 32) {
      f16x8 af[4], bf[4];
#pragma unroll
      for (int i = 0; i < 4; ++i) {
        const int r = wrow + i * 16 + l16;
        const int col = ((kk >> 3) + quad) ^ (l16 & 7);
        af[i] = *(const f16x8*)&lsA[r * 64 + col * 8];
      }
#pragma unroll
      for (int j = 0; j < 4; ++j) {
        const int r = wcol + j * 16 + l16;
        const int col = ((kk >> 3) + quad) ^ (l16 & 7);
        bf[j] = *(const f16x8*)&lsB[r * 64 + col * 8];
      }
#pragma unroll
      for (int i = 0; i < 4; ++i)
#pragma unroll
        for (int j = 0; j < 4; ++j)
          acc[i][j] = __builtin_amdgcn_mfma_f32_16x16x32_f16(af[i], bf[j], acc[i][j], 0, 0, 0);
    }
    __syncthreads();
  }

#pragma unroll
  for (int j = 0; j < 4; ++j) {
    const int c = bn + wcol + j * 16 + l16;
    const float bv = bias[c];
    float s = 0.f, s2 = 0.f;
#pragma unroll
    for (int i = 0; i < 4; ++i) {
      const int r = bm + wrow + i * 16 + quad * 4;
      float* Cp = C + (size_t)r * N + c;
      f32x4 v = acc[i][j];
#pragma unroll
      for (int rr = 0; rr < 4; ++rr) {
        float val = v[rr] + bv;
        Cp[(size_t)rr * N] = val;
        s += val;
        s2 += val * val;
      }
    }
    s  += __shfl_xor(s, 16, 64);  s  += __shfl_xor(s, 32, 64);
    s2 += __shfl_xor(s2, 16, 64); s2 += __shfl_xor(s2, 32, 64);
    if (quad == 0) {
      atomicAdd(&sum[c], s);
      atomicAdd(&sumsq[c], s2);
    }
  }
}

// ---------- finalize from [slot][c] partials: one wave per column ----------
__global__ __launch_bounds__(256) void bn_finalize_wave(const float* __restrict__ psum,
                                                        const float* __restrict__ psumsq,
                                                        const float* __restrict__ gamma,
                                                        const float* __restrict__ beta,
                                                        float* __restrict__ scale,
                                                        float* __restrict__ shift,
                                                        float invB, int S, int D) {
  const int wave = threadIdx.x >> 6;
  const int lane = threadIdx.x & 63;
  const int c = blockIdx.x * 4 + wave;
  float s = 0.f, q = 0.f;
  for (int u = lane; u < S; u += 64) {
    s += psum[(size_t)u * D + c];
    q += psumsq[(size_t)u * D + c];
  }
#pragma unroll
  for (int o = 32; o > 0; o >>= 1) {
    s += __shfl_xor(s, o, 64);
    q += __shfl_xor(q, o, 64);
  }
  if (lane == 0) {
    float mean = s * invB;
    float var  = q * invB - mean * mean;
    float rstd = rsqrtf(var + 1e-5f);
    float sc = rstd * gamma[c];
    scale[c] = sc;
    shift[c] = beta[c] - mean * sc;
  }
}

// ---------- finalize from atomic sums (fallback) ----------
__global__ __launch_bounds__(256) void bn_finalize(const float* __restrict__ sum,
                                                   const float* __restrict__ sumsq,
                                                   const float* __restrict__ gamma,
                                                   const float* __restrict__ beta,
                                                   float* __restrict__ scale,
                                                   float* __restrict__ shift,
                                                   float invB) {
  const int c = blockIdx.x * 256 + threadIdx.x;
  float mean = sum[c] * invB;
  float var  = sumsq[c] * invB - mean * mean;
  float rstd = rsqrtf(var + 1e-5f);
  float sc = rstd * gamma[c];
  scale[c] = sc;
  shift[c] = beta[c] - mean * sc;
}

// ---------- BN + prior + sparsemax: one row per wave, H2 pair-interleaved fp16 ----------
__global__ __launch_bounds__(256) void bn_sparsemax_h2(const _Float16* __restrict__ H2,
                                                       const float* __restrict__ P,
                                                       const float* __restrict__ scale,
                                                       const float* __restrict__ shift,
                                                       float* __restrict__ out, int D) {
  const int wave = threadIdx.x >> 6;
  const int lane = threadIdx.x & 63;
  const int row = blockIdx.x * 4 + wave;
  const int rp  = row >> 1;
  const int par = row & 1;

  const f16x8* Hc = (const f16x8*)(H2 + (size_t)rp * 2 * D);
  const f32x4* P4 = (const f32x4*)(P + (size_t)row * D);
  const f32x4* SC = (const f32x4*)scale;
  const f32x4* SH = (const f32x4*)shift;

  f32x4 z[4];
  float tot = 0.f;
#pragma unroll
  for (int j = 0; j < 4; ++j) {
    const int idx = j * 64 + lane;
    f16x8 h = Hc[idx];
    f32x4 hv = {(float)h[par], (float)h[2 + par], (float)h[4 + par], (float)h[6 + par]};
    f32x4 zz = P4[idx] * (hv * SC[idx] + SH[idx]);
    z[j] = zz;
    tot += zz[0] + zz[1] + zz[2] + zz[3];
  }
#pragma unroll
  for (int o = 32; o > 0; o >>= 1) tot += __shfl_xor(tot, o, 64);

  float tau = (tot - 1.0f) / (float)D;
  float kprev = -1.0f;
  for (int it = 0; it < 64; ++it) {
    float s = 0.f, kf = 0.f;
#pragma unroll
    for (int j = 0; j < 4; ++j)
#pragma unroll
      for (int c = 0; c < 4; ++c) {
        float zz = z[j][c];
        if (zz > tau) { s += zz; kf += 1.0f; }
      }
#pragma unroll
    for (int o = 32; o > 0; o >>= 1) {
      s  += __shfl_xor(s, o, 64);
      kf += __shfl_xor(kf, o, 64);
    }
    tau = (s - 1.0f) / kf;
    if (kf == kprev) break;
    kprev = kf;
  }

  f32x4* O4 = (f32x4*)(out + (size_t)row * D);
#pragma unroll
  for (int j = 0; j < 4; ++j) {
    const int idx = j * 64 + lane;
    f32x4 o;
#pragma unroll
    for (int c = 0; c < 4; ++c) o[c] = fmaxf(z[j][c] - tau, 0.f);
    O4[idx] = o;
  }
}

// ---------- fp32 row-major variant (fallback path) ----------
__global__ __launch_bounds__(256) void bn_sparsemax_f32(const float* __restrict__ H,
                                                        const float* __restrict__ P,
                                                        const float* __restrict__ scale,
                                                        const float* __restrict__ shift,
                                                        float* __restrict__ out, int D) {
  const int wave = threadIdx.x >> 6;
  const int lane = threadIdx.x & 63;
  const int row = blockIdx.x * 4 + wave;
  const size_t rowoff = (size_t)row * D;
  const f32x4* H4 = (const f32x4*)(H + rowoff);
  const f32x4* P4 = (const f32x4*)(P + rowoff);
  const f32x4* SC = (const f32x4*)scale;
  const f32x4* SH = (const f32x4*)shift;

  f32x4 z[4];
  float tot = 0.f;
#pragma unroll
  for (int j = 0; j < 4; ++j) {
    const int idx = j * 64 + lane;
    f32x4 zz = P4[idx] * (H4[idx] * SC[idx] + SH[idx]);
    z[j] = zz;
    tot += zz[0] + zz[1] + zz[2] + zz[3];
  }
#pragma unroll
  for (int o = 32; o > 0; o >>= 1) tot += __shfl_xor(tot, o, 64);

  float tau = (tot - 1.0f) / (float)D;
  float kprev = -1.0f;
  for (int it = 0; it < 64; ++it) {
    float s = 0.f, kf = 0.f;
#pragma unroll
    for (int j = 0; j < 4; ++j)
#pragma unroll
      for (int c = 0; c < 4; ++c) {
        float zz = z[j][c];
        if (zz > tau) { s += zz; kf += 1.0f; }
      }
#pragma unroll
    for (int o = 32; o > 0; o >>= 1) {
      s  += __shfl_xor(s, o, 64);
      kf += __shfl_xor(kf, o, 64);
    }
    tau = (s - 1.0f) / kf;
    if (kf == kprev) break;
    kprev = kf;
  }

  f32x4* O4 = (f32x4*)(out + rowoff);
#pragma unroll
  for (int j = 0; j < 4; ++j) {
    const int idx = j * 64 + lane;
    f32x4 o;
#pragma unroll
    for (int c = 0; c < 4; ++c) o[c] = fmaxf(z[j][c] - tau, 0.f);
    O4[idx] = o;
  }
}

extern "C" void kernel_launch(void* const* d_in, const int* in_sizes, int n_in,
                              void* d_out, int out_size, void* d_ws, size_t ws_size,
                              hipStream_t stream) {
  const float* a     = (const float*)d_in[0];
  const float* p     = (const float*)d_in[1];
  const float* W     = (const float*)d_in[2];
  const float* b     = (const float*)d_in[3];
  const float* gamma = (const float*)d_in[4];
  const float* beta  = (const float*)d_in[5];
  float* out = (float*)d_out;

  const int D = in_sizes[3];           // 1024 (in_sizes are ELEMENT counts: round-0 verified)
  const int Brows = in_sizes[0] / D;   // 32768
  const int K = D, N = D;
  const size_t na = (size_t)Brows * D;
  const size_t nw = (size_t)D * D;
  const int S = (Brows / GBM) * 2;     // partial slots (256)

  // ws layout (~71 MB): [psum S*D][psumsq S*D][scale D][shift D][Wh fp16][H2 fp16]
  // A fp16 (64 MB) lives in d_out (output is na fp32 = 4*na bytes by problem shape;
  // 2*na bytes needed — always fits; do NOT gate on out_size, its unit is unverified
  // and the R1 gate on it silently routed us to the fallback).
  const size_t statsB = (size_t)D * S * sizeof(float);            // 1 MB
  float* psum   = (float*)d_ws;
  float* psumsq = (float*)((char*)d_ws + statsB);
  float* wscale = (float*)((char*)d_ws + 2 * statsB);
  float* wshift = wscale + D;
  const size_t off_Wh = 2 * statsB + 16384;
  _Float16* Wh = (_Float16*)((char*)d_ws + off_Wh);
  _Float16* H2 = Wh + nw;
  const size_t need = off_Wh + (nw + na) * sizeof(_Float16);      // ~71 MB
  _Float16* Ah = (_Float16*)d_out;

  const bool shape_ok = (Brows % GBM) == 0 && ((Brows / GBM) % 8) == 0 &&
                        (N / GBN) == 4 && (N % GBN) == 0 &&
                        (K % GBK) == 0 && (K / GBK) >= 4;

  if (ws_size >= need && shape_ok) {
    cvt_f32_f16<<<dim3(512), 256, 0, stream>>>(W, Wh, nw / 8);
    cvt_f32_f16<<<dim3(2048), 256, 0, stream>>>(a, Ah, na / 8);
    gemm16<<<dim3((Brows / GBM) * (N / GBN)), 512, 0, stream>>>(
        Ah, Wh, b, H2, psum, psumsq, Brows, N, K);
    bn_finalize_wave<<<dim3(D / 4), 256, 0, stream>>>(psum, psumsq, gamma, beta,
                                                      wscale, wshift,
                                                      1.0f / (float)Brows, S, D);
    bn_sparsemax_h2<<<dim3(Brows / 4), 256, 0, stream>>>(H2, p, wscale, wshift, out, D);
  } else {
    // fallback: atomic stats, fp32 H in d_out, in-register cvt of A and W
    float* wsum   = (float*)d_ws;
    float* wsumsq = wsum + D;
    float* fscale = wsum + 2 * D;
    float* fshift = wsum + 3 * D;
    hipMemsetAsync(d_ws, 0, 2 * D * sizeof(float), stream);
    gemm_fallback<<<dim3(N / BN, Brows / BM), 256, 0, stream>>>(
        a, W, b, out, wsum, wsumsq, Brows, N, K);
    bn_finalize<<<dim3(D / 256), 256, 0, stream>>>(wsum, wsumsq, gamma, beta, fscale, fshift,
                                                   1.0f / (float)Brows);
    bn_sparsemax_f32<<<dim3(Brows / 4), 256, 0, stream>>>(out, p, fscale, fshift, out, D);
  }
}